// Round 3
// baseline (57.642 us; speedup 1.0000x reference)
//
#include <hip/hip_runtime.h>

#define EPSF 1e-5f

typedef float f32x4 __attribute__((ext_vector_type(4)));

// B=8,E=16,N=64 -> 8192 series, T=128, D=32 hidden, OUT=64 output channels.
// Per series x[T]:
//   y1[d][t] = relu(a[d] conv x + c1[d])            (BN1 folded, pad=1)
//   y2[t]    = relu(sum_d w2f[d] conv y1[d] + c2)   (BN2 folded, pad=1 on y1!)
//   out[o][t]= w3[o]*y2[t] + b3[o]
// Write-BW-bound: 256 MiB output; fillBuffer ceiling ~7 TB/s -> ~38 us floor.
// y1 is recomputed per-thread in registers (3 taps needed per d), never staged:
// LDS ~1.5 KB/block -> full occupancy; one barrier less on the pre-store path.

__global__ __launch_bounds__(128) void hnc_kernel(
    const float* __restrict__ x_in,   // [S][128]
    const float* __restrict__ w1,     // [32][1][3]
    const float* __restrict__ b1,     // [32]
    const float* __restrict__ w2,     // [1][32][3]
    const float* __restrict__ b2,     // [1]
    const float* __restrict__ w3,     // [64]
    const float* __restrict__ b3,     // [64]
    const float* __restrict__ g1, const float* __restrict__ be1,
    const float* __restrict__ m1, const float* __restrict__ v1,
    const float* __restrict__ g2, const float* __restrict__ be2,
    const float* __restrict__ m2, const float* __restrict__ v2,
    float* __restrict__ out)          // [S][64][128]
{
    const int T = 128, OUT = 64;

    __shared__ float x_s[132];        // 2-zero halo both ends (x[-2..-1], x[128..129])
    __shared__ float y2_s[128];
    __shared__ float a1_s[3][32];     // BN1-folded conv1 weights
    __shared__ float c1_s[32];        // BN1-folded conv1 bias
    __shared__ float w2f_s[3][32];    // BN2-scale-folded conv2 weights
    __shared__ float w3_s[64];
    __shared__ float b3_s[64];
    __shared__ float c2_s;

    const int tid = threadIdx.x;      // = t position
    const int series = blockIdx.x;

    // ---- Phase A: stage x + fold params ----
    x_s[2 + tid] = x_in[(size_t)series * T + tid];
    if (tid < 2) x_s[tid] = 0.f;
    else if (tid < 4) x_s[128 + tid] = 0.f;   // 130, 131

    if (tid < 32) {
        float inv = g1[tid] * rsqrtf(v1[tid] + EPSF);
        a1_s[0][tid] = inv * w1[tid * 3 + 0];
        a1_s[1][tid] = inv * w1[tid * 3 + 1];
        a1_s[2][tid] = inv * w1[tid * 3 + 2];
        c1_s[tid] = b1[tid] * inv + be1[tid] - m1[tid] * inv;
    } else if (tid < 64) {
        int d = tid - 32;
        float s2 = g2[0] * rsqrtf(v2[0] + EPSF);
        w2f_s[0][d] = s2 * w2[d * 3 + 0];
        w2f_s[1][d] = s2 * w2[d * 3 + 1];
        w2f_s[2][d] = s2 * w2[d * 3 + 2];
        if (d == 0) c2_s = b2[0] * s2 + be2[0] - m2[0] * s2;
    } else if (tid < 128) {
        int o = tid - 64;
        w3_s[o] = w3[o];
        b3_s[o] = b3[o];
    }
    __syncthreads();

    // ---- Phase B: y2[t] per-thread in registers ----
    // Need y1[d][t-1], y1[d][t], y1[d][t+1]; each from x[t-2..t+2].
    // Edge taps (t==0 left, t==127 right) are conv2 *padding* zeros of y1,
    // NOT y1 computed from zero-padded x -> mask them.
    const float xm2 = x_s[tid];     // x[t-2]
    const float xm1 = x_s[tid + 1];
    const float x0  = x_s[tid + 2];
    const float xp1 = x_s[tid + 3];
    const float xp2 = x_s[tid + 4];

    float accm = 0.f, acc0 = 0.f, accp = 0.f;
    #pragma unroll
    for (int d = 0; d < 32; ++d) {
        const float a0 = a1_s[0][d], a1 = a1_s[1][d], a2 = a1_s[2][d];
        const float c  = c1_s[d];
        float ym = fmaxf(fmaf(a0, xm2, fmaf(a1, xm1, fmaf(a2, x0,  c))), 0.f);
        float y0 = fmaxf(fmaf(a0, xm1, fmaf(a1, x0,  fmaf(a2, xp1, c))), 0.f);
        float yp = fmaxf(fmaf(a0, x0,  fmaf(a1, xp1, fmaf(a2, xp2, c))), 0.f);
        accm = fmaf(w2f_s[0][d], ym, accm);
        acc0 = fmaf(w2f_s[1][d], y0, acc0);
        accp = fmaf(w2f_s[2][d], yp, accp);
    }
    const float mm = (tid == 0)   ? 0.f : 1.f;   // y1[d][-1] pad
    const float mp = (tid == 127) ? 0.f : 1.f;   // y1[d][128] pad
    y2_s[tid] = fmaxf(fmaf(mm, accm, fmaf(mp, accp, acc0 + c2_s)), 0.f);
    __syncthreads();

    // ---- Phase C: streaming float4 stores, nontemporal ----
    f32x4* out4 = (f32x4*)(out + (size_t)series * OUT * T);
    #pragma unroll
    for (int i = 0; i < 16; ++i) {
        int flat4 = i * 128 + tid;             // float4 index within series
        int o = flat4 >> 5;                    // (flat4*4)/128
        int t = (flat4 << 2) & 127;
        f32x4 y = *(const f32x4*)&y2_s[t];
        float w = w3_s[o], b = b3_s[o];
        f32x4 r;
        r.x = fmaf(w, y.x, b);
        r.y = fmaf(w, y.y, b);
        r.z = fmaf(w, y.z, b);
        r.w = fmaf(w, y.w, b);
        __builtin_nontemporal_store(r, &out4[flat4]);
    }
}

extern "C" void kernel_launch(void* const* d_in, const int* in_sizes, int n_in,
                              void* d_out, int out_size, void* d_ws, size_t ws_size,
                              hipStream_t stream) {
    const float* x   = (const float*)d_in[0];   // node_features [B,E,N,T,1]
    // d_in[1] edge_features: unused by the reference computation
    const float* w1  = (const float*)d_in[2];
    const float* b1  = (const float*)d_in[3];
    const float* w2  = (const float*)d_in[4];
    const float* b2  = (const float*)d_in[5];
    const float* w3  = (const float*)d_in[6];
    const float* b3  = (const float*)d_in[7];
    const float* g1  = (const float*)d_in[8];
    const float* be1 = (const float*)d_in[9];
    const float* m1  = (const float*)d_in[10];
    const float* v1  = (const float*)d_in[11];
    const float* g2  = (const float*)d_in[12];
    const float* be2 = (const float*)d_in[13];
    const float* m2  = (const float*)d_in[14];
    const float* v2  = (const float*)d_in[15];

    const int T = 128;
    const int n_series = in_sizes[0] / T;       // 8192

    hnc_kernel<<<n_series, 128, 0, stream>>>(x, w1, b1, w2, b2, w3, b3,
                                             g1, be1, m1, v1, g2, be2, m2, v2,
                                             (float*)d_out);
}

// Round 4
// 51.935 us; speedup vs baseline: 1.1099x; 1.1099x over previous
//
#include <hip/hip_runtime.h>

#define EPSF 1e-5f

typedef float f32x4 __attribute__((ext_vector_type(4)));

// B=8,E=16,N=64 -> 8192 series, T=128, D=32 hidden, OUT=64 output channels.
// Per series x[T]:
//   y1[d][t] = relu(a[d] conv x + c1[d])            (BN1 folded, pad=1)
//   y2[t]    = relu(sum_d w2f[d] conv y1[d] + c2)   (BN2 folded, pad=1 on y1!)
//   out[o][t]= w3[o]*y2[t] + b3[o]
// Write-BW-bound: 256 MiB output; fill-kernel ceiling ~6.9 TB/s -> ~39 us floor.
// y1 recomputed per-thread in registers (3 taps per d), never staged.
// Plain (cached) stores: fillBuffer hits 87% peak through L2; nt stores
// measured SLOWER (r3: 57.6us vs r1 54.4us) -> reverted.
// Unroll capped at 4 to keep VGPRs low (weights stay LDS-resident).

__global__ __launch_bounds__(128) void hnc_kernel(
    const float* __restrict__ x_in,   // [S][128]
    const float* __restrict__ w1,     // [32][1][3]
    const float* __restrict__ b1,     // [32]
    const float* __restrict__ w2,     // [1][32][3]
    const float* __restrict__ b2,     // [1]
    const float* __restrict__ w3,     // [64]
    const float* __restrict__ b3,     // [64]
    const float* __restrict__ g1, const float* __restrict__ be1,
    const float* __restrict__ m1, const float* __restrict__ v1,
    const float* __restrict__ g2, const float* __restrict__ be2,
    const float* __restrict__ m2, const float* __restrict__ v2,
    float* __restrict__ out)          // [S][64][128]
{
    const int T = 128, OUT = 64;

    __shared__ float x_s[132];        // 2-zero halo both ends
    __shared__ float y2_s[128];
    __shared__ float a1_s[3][32];     // BN1-folded conv1 weights
    __shared__ float c1_s[32];        // BN1-folded conv1 bias
    __shared__ float w2f_s[3][32];    // BN2-scale-folded conv2 weights
    __shared__ float w3_s[64];
    __shared__ float b3_s[64];
    __shared__ float c2_s;

    const int tid = threadIdx.x;      // = t position
    const int series = blockIdx.x;

    // ---- Phase A: stage x + fold params ----
    x_s[2 + tid] = x_in[(size_t)series * T + tid];
    if (tid < 2) x_s[tid] = 0.f;
    else if (tid < 4) x_s[128 + tid] = 0.f;   // 130, 131

    if (tid < 32) {
        float inv = g1[tid] * rsqrtf(v1[tid] + EPSF);
        a1_s[0][tid] = inv * w1[tid * 3 + 0];
        a1_s[1][tid] = inv * w1[tid * 3 + 1];
        a1_s[2][tid] = inv * w1[tid * 3 + 2];
        c1_s[tid] = b1[tid] * inv + be1[tid] - m1[tid] * inv;
    } else if (tid < 64) {
        int d = tid - 32;
        float s2 = g2[0] * rsqrtf(v2[0] + EPSF);
        w2f_s[0][d] = s2 * w2[d * 3 + 0];
        w2f_s[1][d] = s2 * w2[d * 3 + 1];
        w2f_s[2][d] = s2 * w2[d * 3 + 2];
        if (d == 0) c2_s = b2[0] * s2 + be2[0] - m2[0] * s2;
    } else if (tid < 128) {
        int o = tid - 64;
        w3_s[o] = w3[o];
        b3_s[o] = b3[o];
    }
    __syncthreads();

    // ---- Phase B: y2[t] per-thread in registers ----
    // Need y1[d][t-1..t+1]; each from x[t-2..t+2]. The t==0/t==127 edge taps
    // are conv2 padding zeros of y1 (NOT y1 of padded x) -> masked after.
    const float xm2 = x_s[tid];
    const float xm1 = x_s[tid + 1];
    const float x0  = x_s[tid + 2];
    const float xp1 = x_s[tid + 3];
    const float xp2 = x_s[tid + 4];

    float accm = 0.f, acc0 = 0.f, accp = 0.f;
    #pragma unroll 4
    for (int d = 0; d < 32; ++d) {
        const float a0 = a1_s[0][d], a1 = a1_s[1][d], a2 = a1_s[2][d];
        const float c  = c1_s[d];
        float ym = fmaxf(fmaf(a0, xm2, fmaf(a1, xm1, fmaf(a2, x0,  c))), 0.f);
        float y0 = fmaxf(fmaf(a0, xm1, fmaf(a1, x0,  fmaf(a2, xp1, c))), 0.f);
        float yp = fmaxf(fmaf(a0, x0,  fmaf(a1, xp1, fmaf(a2, xp2, c))), 0.f);
        accm = fmaf(w2f_s[0][d], ym, accm);
        acc0 = fmaf(w2f_s[1][d], y0, acc0);
        accp = fmaf(w2f_s[2][d], yp, accp);
    }
    const float mm = (tid == 0)   ? 0.f : 1.f;   // y1[d][-1] pad
    const float mp = (tid == 127) ? 0.f : 1.f;   // y1[d][128] pad
    y2_s[tid] = fmaxf(fmaf(mm, accm, fmaf(mp, accp, acc0 + c2_s)), 0.f);
    __syncthreads();

    // ---- Phase C: plain float4 coalesced stores ----
    f32x4* out4 = (f32x4*)(out + (size_t)series * OUT * T);
    #pragma unroll
    for (int i = 0; i < 16; ++i) {
        int flat4 = i * 128 + tid;             // float4 index within series
        int o = flat4 >> 5;                    // (flat4*4)/128
        int t = (flat4 << 2) & 127;
        f32x4 y = *(const f32x4*)&y2_s[t];
        float w = w3_s[o], b = b3_s[o];
        f32x4 r;
        r.x = fmaf(w, y.x, b);
        r.y = fmaf(w, y.y, b);
        r.z = fmaf(w, y.z, b);
        r.w = fmaf(w, y.w, b);
        out4[flat4] = r;
    }
}

extern "C" void kernel_launch(void* const* d_in, const int* in_sizes, int n_in,
                              void* d_out, int out_size, void* d_ws, size_t ws_size,
                              hipStream_t stream) {
    const float* x   = (const float*)d_in[0];   // node_features [B,E,N,T,1]
    // d_in[1] edge_features: unused by the reference computation
    const float* w1  = (const float*)d_in[2];
    const float* b1  = (const float*)d_in[3];
    const float* w2  = (const float*)d_in[4];
    const float* b2  = (const float*)d_in[5];
    const float* w3  = (const float*)d_in[6];
    const float* b3  = (const float*)d_in[7];
    const float* g1  = (const float*)d_in[8];
    const float* be1 = (const float*)d_in[9];
    const float* m1  = (const float*)d_in[10];
    const float* v1  = (const float*)d_in[11];
    const float* g2  = (const float*)d_in[12];
    const float* be2 = (const float*)d_in[13];
    const float* m2  = (const float*)d_in[14];
    const float* v2  = (const float*)d_in[15];

    const int T = 128;
    const int n_series = in_sizes[0] / T;       // 8192

    hnc_kernel<<<n_series, 128, 0, stream>>>(x, w1, b1, w2, b2, w3, b3,
                                             g1, be1, m1, v1, g2, be2, m2, v2,
                                             (float*)d_out);
}

// Round 5
// 50.832 us; speedup vs baseline: 1.1340x; 1.0217x over previous
//
#include <hip/hip_runtime.h>

#define EPSF 1e-5f
#define SER 4   // series per block; grid = 8192/SER = 2048 (all-resident)

typedef float f32x4 __attribute__((ext_vector_type(4)));

// B=8,E=16,N=64 -> 8192 series, T=128, D=32 hidden, OUT=64 output channels.
// Per series x[T]:
//   y1[d][t] = relu(a[d] conv x + c1[d])            (BN1 folded, pad=1)
//   y2[t]    = relu(sum_d w2f[d] conv y1[d] + c2)   (BN2 folded, pad=1 on y1!)
//   out[o][t]= w3[o]*y2[t] + b3[o]
// Write-BW-bound: 256 MiB output; fill-kernel ceiling ~6.9 TB/s -> ~39 us floor.
// r4 = 51.9us (5.2 TB/s). Overhead levers this round:
//  - SER=4 series/block: param-fold prologue amortized 4x, 2048 blocks.
//  - weights packed as f32x4 -> 64 ds_read_b128 in phase B vs 224 ds_read_b32.
//  - store phase: y2 quad + (o mod 4) are thread-invariant -> 1 LDS read, not 16.
//  - x double-buffered + register-prefetched under the store phase.

__global__ __launch_bounds__(128) void hnc_kernel(
    const float* __restrict__ x_in,   // [S][128]
    const float* __restrict__ w1,     // [32][1][3]
    const float* __restrict__ b1,     // [32]
    const float* __restrict__ w2,     // [1][32][3]
    const float* __restrict__ b2,     // [1]
    const float* __restrict__ w3,     // [64]
    const float* __restrict__ b3,     // [64]
    const float* __restrict__ g1, const float* __restrict__ be1,
    const float* __restrict__ m1, const float* __restrict__ v1,
    const float* __restrict__ g2, const float* __restrict__ be2,
    const float* __restrict__ m2, const float* __restrict__ v2,
    float* __restrict__ out)          // [S][64][128]
{
    __shared__ float x_s[2][132];     // 2-zero halo both ends, double-buffered
    __shared__ float y2_s[2][128];    // double-buffered
    __shared__ f32x4 pkA_s[32];       // {a0,a1,a2,c1}  (BN1-folded conv1)
    __shared__ f32x4 pkB_s[32];       // {w20,w21,w22,0} (BN2-scale-folded conv2)
    __shared__ float w3_s[64];
    __shared__ float b3_s[64];
    __shared__ float c2_s;

    const int tid = threadIdx.x;      // = t position
    const size_t s0 = (size_t)blockIdx.x * SER;

    // ---- Prologue: stage x[0] + fold params (once per SER series) ----
    x_s[0][2 + tid] = x_in[s0 * 128 + tid];
    if (tid < 2)      { x_s[0][tid] = 0.f;       x_s[1][tid] = 0.f; }
    else if (tid < 4) { x_s[0][128 + tid] = 0.f; x_s[1][128 + tid] = 0.f; }

    if (tid < 32) {
        const int d = tid;
        float inv = g1[d] * rsqrtf(v1[d] + EPSF);
        f32x4 A;
        A.x = inv * w1[d * 3 + 0];
        A.y = inv * w1[d * 3 + 1];
        A.z = inv * w1[d * 3 + 2];
        A.w = b1[d] * inv + be1[d] - m1[d] * inv;
        pkA_s[d] = A;
    } else if (tid < 64) {
        const int d = tid - 32;
        float s2 = g2[0] * rsqrtf(v2[0] + EPSF);
        f32x4 W;
        W.x = s2 * w2[d * 3 + 0];
        W.y = s2 * w2[d * 3 + 1];
        W.z = s2 * w2[d * 3 + 2];
        W.w = 0.f;
        pkB_s[d] = W;
        if (d == 0) c2_s = b2[0] * s2 + be2[0] - m2[0] * s2;
    } else {
        const int o = tid - 64;
        w3_s[o] = w3[o];
        b3_s[o] = b3[o];
    }
    __syncthreads();

    const float mm = (tid == 0)   ? 0.f : 1.f;   // y1[d][-1] conv2-pad
    const float mp = (tid == 127) ? 0.f : 1.f;   // y1[d][128] conv2-pad
    const int   og = tid >> 5;                   // o mod 4 residue, fixed/thread
    const int   ty = (tid << 2) & 127;           // y2 quad index, fixed/thread

    for (int s = 0; s < SER; ++s) {
        const int cur = s & 1, nxt = cur ^ 1;

        // prefetch next series' x into a register (hides under store drain)
        float xpre = 0.f;
        if (s + 1 < SER) xpre = x_in[(s0 + s + 1) * 128 + tid];

        // ---- Phase B: y2[t] in registers; y1 recomputed (3 taps per d) ----
        const float xm2 = x_s[cur][tid];
        const float xm1 = x_s[cur][tid + 1];
        const float x0  = x_s[cur][tid + 2];
        const float xp1 = x_s[cur][tid + 3];
        const float xp2 = x_s[cur][tid + 4];

        float accm = 0.f, acc0 = 0.f, accp = 0.f;
        #pragma unroll 4
        for (int d = 0; d < 32; ++d) {
            const f32x4 A = pkA_s[d];
            const f32x4 W = pkB_s[d];
            float ym = fmaxf(fmaf(A.x, xm2, fmaf(A.y, xm1, fmaf(A.z, x0,  A.w))), 0.f);
            float y0 = fmaxf(fmaf(A.x, xm1, fmaf(A.y, x0,  fmaf(A.z, xp1, A.w))), 0.f);
            float yp = fmaxf(fmaf(A.x, x0,  fmaf(A.y, xp1, fmaf(A.z, xp2, A.w))), 0.f);
            accm = fmaf(W.x, ym, accm);
            acc0 = fmaf(W.y, y0, acc0);
            accp = fmaf(W.z, yp, accp);
        }
        y2_s[cur][tid] = fmaxf(fmaf(mm, accm, fmaf(mp, accp, acc0 + c2_s)), 0.f);
        __syncthreads();

        // ---- Phase C: streaming f32x4 stores; y2 quad is loop-invariant ----
        const f32x4 y = *(const f32x4*)&y2_s[cur][ty];
        f32x4* out4 = (f32x4*)(out + (s0 + s) * 64 * 128);
        #pragma unroll
        for (int i = 0; i < 16; ++i) {
            const int o = 4 * i + og;
            const float w = w3_s[o], b = b3_s[o];
            f32x4 r;
            r.x = fmaf(w, y.x, b);
            r.y = fmaf(w, y.y, b);
            r.z = fmaf(w, y.z, b);
            r.w = fmaf(w, y.w, b);
            out4[i * 128 + tid] = r;
        }

        // stage prefetched x for next series; barrier publishes it and
        // retires this iteration's y2 reads before buffer reuse at s+2
        if (s + 1 < SER) {
            x_s[nxt][2 + tid] = xpre;
            __syncthreads();
        }
    }
}

extern "C" void kernel_launch(void* const* d_in, const int* in_sizes, int n_in,
                              void* d_out, int out_size, void* d_ws, size_t ws_size,
                              hipStream_t stream) {
    const float* x   = (const float*)d_in[0];   // node_features [B,E,N,T,1]
    // d_in[1] edge_features: unused by the reference computation
    const float* w1  = (const float*)d_in[2];
    const float* b1  = (const float*)d_in[3];
    const float* w2  = (const float*)d_in[4];
    const float* b2  = (const float*)d_in[5];
    const float* w3  = (const float*)d_in[6];
    const float* b3  = (const float*)d_in[7];
    const float* g1  = (const float*)d_in[8];
    const float* be1 = (const float*)d_in[9];
    const float* m1  = (const float*)d_in[10];
    const float* v1  = (const float*)d_in[11];
    const float* g2  = (const float*)d_in[12];
    const float* be2 = (const float*)d_in[13];
    const float* m2  = (const float*)d_in[14];
    const float* v2  = (const float*)d_in[15];

    const int T = 128;
    const int n_series = in_sizes[0] / T;       // 8192
    const int n_blocks = n_series / SER;        // 2048

    hnc_kernel<<<n_blocks, 128, 0, stream>>>(x, w1, b1, w2, b2, w3, b3,
                                             g1, be1, m1, v1, g2, be2, m2, v2,
                                             (float*)d_out);
}

// Round 6
// 50.493 us; speedup vs baseline: 1.1416x; 1.0067x over previous
//
#include <hip/hip_runtime.h>

#define EPSF 1e-5f
#define SER 4   // series per block; grid = 8192/SER = 2048

typedef float f32x4 __attribute__((ext_vector_type(4)));

// B=8,E=16,N=64 -> 8192 series, T=128, D=32 hidden, OUT=64 output channels.
// Per series x[T]:
//   y1[d][t] = relu(a[d] conv x + c1[d])            (BN1 folded, pad=1)
//   y2[t]    = relu(sum_d w2f[d] conv y1[d] + c2)   (BN2 folded, pad=1 on y1!)
//   out[o][t]= w3[o]*y2[t] + b3[o]
// Write-BW-bound: 256 MiB out; fill-kernel ceiling ~6.9 TB/s -> ~39 us floor.
// r5 = 50.8us. This round: fuse all 4 series into ONE phase B so each weight
// ds_read_b128 is used 4x (LDS pipe 49k -> ~12k cyc/CU), then one
// uninterrupted 64-store burst. 2 barriers total (was 7), no mid-loop
// vmcnt(0) store drains.

__global__ __launch_bounds__(128) void hnc_kernel(
    const float* __restrict__ x_in,   // [S][128]
    const float* __restrict__ w1,     // [32][1][3]
    const float* __restrict__ b1,     // [32]
    const float* __restrict__ w2,     // [1][32][3]
    const float* __restrict__ b2,     // [1]
    const float* __restrict__ w3,     // [64]
    const float* __restrict__ b3,     // [64]
    const float* __restrict__ g1, const float* __restrict__ be1,
    const float* __restrict__ m1, const float* __restrict__ v1,
    const float* __restrict__ g2, const float* __restrict__ be2,
    const float* __restrict__ m2, const float* __restrict__ v2,
    float* __restrict__ out)          // [S][64][128]
{
    __shared__ float x_s[SER][132];   // 2-zero halo both ends
    __shared__ float y2_s[SER][128];
    __shared__ f32x4 pkA_s[32];       // {a0,a1,a2,c1}  (BN1-folded conv1)
    __shared__ f32x4 pkB_s[32];       // {w20,w21,w22,0} (BN2-folded conv2)
    __shared__ float w3_s[64];
    __shared__ float b3_s[64];
    __shared__ float c2_s;

    const int tid = threadIdx.x;      // = t position
    const size_t s0 = (size_t)blockIdx.x * SER;

    // ---- Prologue: stage 4 series' x + fold params ----
    #pragma unroll
    for (int s = 0; s < SER; ++s)
        x_s[s][2 + tid] = x_in[(s0 + s) * 128 + tid];
    if (tid < SER) {
        x_s[tid][0] = 0.f; x_s[tid][1] = 0.f;
        x_s[tid][130] = 0.f; x_s[tid][131] = 0.f;
    }

    if (tid >= 32 && tid < 64) {
        const int d = tid - 32;
        float inv = g1[d] * rsqrtf(v1[d] + EPSF);
        f32x4 A;
        A.x = inv * w1[d * 3 + 0];
        A.y = inv * w1[d * 3 + 1];
        A.z = inv * w1[d * 3 + 2];
        A.w = b1[d] * inv + be1[d] - m1[d] * inv;
        pkA_s[d] = A;
    } else if (tid >= 64 && tid < 96) {
        const int d = tid - 64;
        float s2 = g2[0] * rsqrtf(v2[0] + EPSF);
        f32x4 W;
        W.x = s2 * w2[d * 3 + 0];
        W.y = s2 * w2[d * 3 + 1];
        W.z = s2 * w2[d * 3 + 2];
        W.w = 0.f;
        pkB_s[d] = W;
        if (d == 0) c2_s = b2[0] * s2 + be2[0] - m2[0] * s2;
    } else if (tid >= 96) {
        const int o = (tid - 96) * 2;
        w3_s[o] = w3[o];     w3_s[o + 1] = w3[o + 1];
        b3_s[o] = b3[o];     b3_s[o + 1] = b3[o + 1];
    }
    __syncthreads();

    // ---- Phase B: y2[t] for ALL 4 series; each weight read used 4x ----
    float xm2[SER], xm1[SER], x0[SER], xp1[SER], xp2[SER];
    float accm[SER], acc0[SER], accp[SER];
    #pragma unroll
    for (int s = 0; s < SER; ++s) {
        xm2[s] = x_s[s][tid];
        xm1[s] = x_s[s][tid + 1];
        x0[s]  = x_s[s][tid + 2];
        xp1[s] = x_s[s][tid + 3];
        xp2[s] = x_s[s][tid + 4];
        accm[s] = 0.f; acc0[s] = 0.f; accp[s] = 0.f;
    }

    #pragma unroll 4
    for (int d = 0; d < 32; ++d) {
        const f32x4 A = pkA_s[d];
        const f32x4 W = pkB_s[d];
        #pragma unroll
        for (int s = 0; s < SER; ++s) {
            float ym = fmaxf(fmaf(A.x, xm2[s], fmaf(A.y, xm1[s], fmaf(A.z, x0[s],  A.w))), 0.f);
            float y0 = fmaxf(fmaf(A.x, xm1[s], fmaf(A.y, x0[s],  fmaf(A.z, xp1[s], A.w))), 0.f);
            float yp = fmaxf(fmaf(A.x, x0[s],  fmaf(A.y, xp1[s], fmaf(A.z, xp2[s], A.w))), 0.f);
            accm[s] = fmaf(W.x, ym, accm[s]);
            acc0[s] = fmaf(W.y, y0, acc0[s]);
            accp[s] = fmaf(W.z, yp, accp[s]);
        }
    }

    const float mm = (tid == 0)   ? 0.f : 1.f;   // y1[d][-1] conv2-pad
    const float mp = (tid == 127) ? 0.f : 1.f;   // y1[d][128] conv2-pad
    #pragma unroll
    for (int s = 0; s < SER; ++s)
        y2_s[s][tid] = fmaxf(fmaf(mm, accm[s], fmaf(mp, accp[s], acc0[s] + c2_s)), 0.f);
    __syncthreads();

    // ---- Phase C: one uninterrupted 64-store burst ----
    const int og = tid >> 5;                 // o mod 4 residue, fixed/thread
    const int ty = (tid << 2) & 127;         // y2 quad index, fixed/thread
    #pragma unroll
    for (int s = 0; s < SER; ++s) {
        const f32x4 y = *(const f32x4*)&y2_s[s][ty];
        f32x4* out4 = (f32x4*)(out + (s0 + s) * 64 * 128);
        #pragma unroll
        for (int i = 0; i < 16; ++i) {
            const int o = 4 * i + og;
            const float w = w3_s[o], b = b3_s[o];
            f32x4 r;
            r.x = fmaf(w, y.x, b);
            r.y = fmaf(w, y.y, b);
            r.z = fmaf(w, y.z, b);
            r.w = fmaf(w, y.w, b);
            out4[i * 128 + tid] = r;
        }
    }
}

extern "C" void kernel_launch(void* const* d_in, const int* in_sizes, int n_in,
                              void* d_out, int out_size, void* d_ws, size_t ws_size,
                              hipStream_t stream) {
    const float* x   = (const float*)d_in[0];   // node_features [B,E,N,T,1]
    // d_in[1] edge_features: unused by the reference computation
    const float* w1  = (const float*)d_in[2];
    const float* b1  = (const float*)d_in[3];
    const float* w2  = (const float*)d_in[4];
    const float* b2  = (const float*)d_in[5];
    const float* w3  = (const float*)d_in[6];
    const float* b3  = (const float*)d_in[7];
    const float* g1  = (const float*)d_in[8];
    const float* be1 = (const float*)d_in[9];
    const float* m1  = (const float*)d_in[10];
    const float* v1  = (const float*)d_in[11];
    const float* g2  = (const float*)d_in[12];
    const float* be2 = (const float*)d_in[13];
    const float* m2  = (const float*)d_in[14];
    const float* v2  = (const float*)d_in[15];

    const int T = 128;
    const int n_series = in_sizes[0] / T;       // 8192
    const int n_blocks = n_series / SER;        // 2048

    hnc_kernel<<<n_blocks, 128, 0, stream>>>(x, w1, b1, w2, b2, w3, b3,
                                             g1, be1, m1, v1, g2, be2, m2, v2,
                                             (float*)d_out);
}

// Round 7
// 49.549 us; speedup vs baseline: 1.1633x; 1.0191x over previous
//
#include <hip/hip_runtime.h>

#define EPSF 1e-5f
#define SER 4   // series per block; grid = 8192/SER = 2048

typedef float f32x4 __attribute__((ext_vector_type(4)));

// B=8,E=16,N=64 -> 8192 series, T=128, D=32 hidden, OUT=64 output channels.
//   y1[d][t] = relu(a[d] conv x + c1[d])            (BN1 folded, pad=1)
//   y2[t]    = relu(sum_d w2f[d] conv y1[d] + c2)   (BN2 folded, pad=1 on y1!)
//   out[o][t]= w3[o]*y2[t] + b3[o]
// Write-BW-bound: 256 MiB out; fill ceiling ~6.9 TB/s -> ~39 us floor.
// r6 = 50.5us. Diagnosis: compute and store were barrier-serialized (every
// __syncthreads after stores forces vmcnt(0) drain; all blocks lockstep).
// This round: ZERO barriers after prologue. The y2->store-layout exchange is
// wave-local: wave w computes y2[w*64+lane] and stores quads [w*16..w*16+15],
// so 4 __shfl's (wave-synchronous) replace the LDS bounce + barrier. Series
// s+1 compute overlaps series s store drain continuously.

__global__ __launch_bounds__(128) void hnc_kernel(
    const float* __restrict__ x_in,   // [S][128]
    const float* __restrict__ w1,     // [32][1][3]
    const float* __restrict__ b1,     // [32]
    const float* __restrict__ w2,     // [1][32][3]
    const float* __restrict__ b2,     // [1]
    const float* __restrict__ w3,     // [64]
    const float* __restrict__ b3,     // [64]
    const float* __restrict__ g1, const float* __restrict__ be1,
    const float* __restrict__ m1, const float* __restrict__ v1,
    const float* __restrict__ g2, const float* __restrict__ be2,
    const float* __restrict__ m2, const float* __restrict__ v2,
    float* __restrict__ out)          // [S][64][128]
{
    __shared__ float x_s[SER][132];   // 2-zero halo both ends (read-only after prologue)
    __shared__ f32x4 pkA_s[32];       // {a0,a1,a2,c1}  (BN1-folded conv1)
    __shared__ f32x4 pkB_s[32];       // {w20,w21,w22,0} (BN2-folded conv2)
    __shared__ float w3_s[64];
    __shared__ float b3_s[64];
    __shared__ float c2_s;

    const int tid  = threadIdx.x;     // = y2 position p this thread computes
    const int lane = tid & 63;
    const size_t s0 = (size_t)blockIdx.x * SER;

    // ---- Prologue: stage 4 series' x + fold params; the ONLY barrier ----
    #pragma unroll
    for (int s = 0; s < SER; ++s)
        x_s[s][2 + tid] = x_in[(s0 + s) * 128 + tid];
    if (tid < SER) {
        x_s[tid][0] = 0.f; x_s[tid][1] = 0.f;
        x_s[tid][130] = 0.f; x_s[tid][131] = 0.f;
    }
    if (tid < 32) {
        const int d = tid;
        float inv = g1[d] * rsqrtf(v1[d] + EPSF);
        f32x4 A;
        A.x = inv * w1[d * 3 + 0];
        A.y = inv * w1[d * 3 + 1];
        A.z = inv * w1[d * 3 + 2];
        A.w = b1[d] * inv + be1[d] - m1[d] * inv;
        pkA_s[d] = A;
    } else if (tid < 64) {
        const int d = tid - 32;
        float s2 = g2[0] * rsqrtf(v2[0] + EPSF);
        f32x4 W;
        W.x = s2 * w2[d * 3 + 0];
        W.y = s2 * w2[d * 3 + 1];
        W.z = s2 * w2[d * 3 + 2];
        W.w = 0.f;
        pkB_s[d] = W;
        if (d == 0) c2_s = b2[0] * s2 + be2[0] - m2[0] * s2;
    } else {
        const int o = tid - 64;
        w3_s[o] = w3[o];
        b3_s[o] = b3[o];
    }
    __syncthreads();

    // ---- Per-block store-side constants (registers) ----
    const int g  = lane >> 4;                      // o-residue mod 4
    const int qq = (tid >> 6) * 16 + (lane & 15);  // quad index this thread stores
    const int srcl = 4 * (lane & 15);              // shfl source base (wave-local)
    float w3r[16], b3r[16];
    #pragma unroll
    for (int i = 0; i < 16; ++i) {                 // broadcast reads, conflict-free
        w3r[i] = w3_s[4 * i + g];
        b3r[i] = b3_s[4 * i + g];
    }
    const float mm = (tid == 0)   ? 0.f : 1.f;     // y1[d][-1] conv2-pad
    const float mp = (tid == 127) ? 0.f : 1.f;     // y1[d][128] conv2-pad
    const float c2 = c2_s;

    // ---- Pipelined series loop: NO barriers, stores never drained ----
    for (int s = 0; s < SER; ++s) {
        const float xm2 = x_s[s][tid];
        const float xm1 = x_s[s][tid + 1];
        const float x0  = x_s[s][tid + 2];
        const float xp1 = x_s[s][tid + 3];
        const float xp2 = x_s[s][tid + 4];

        float accm = 0.f, acc0 = 0.f, accp = 0.f;
        #pragma unroll 4
        for (int d = 0; d < 32; ++d) {
            const f32x4 A = pkA_s[d];
            const f32x4 W = pkB_s[d];
            float ym = fmaxf(fmaf(A.x, xm2, fmaf(A.y, xm1, fmaf(A.z, x0,  A.w))), 0.f);
            float y0 = fmaxf(fmaf(A.x, xm1, fmaf(A.y, x0,  fmaf(A.z, xp1, A.w))), 0.f);
            float yp = fmaxf(fmaf(A.x, x0,  fmaf(A.y, xp1, fmaf(A.z, xp2, A.w))), 0.f);
            accm = fmaf(W.x, ym, accm);
            acc0 = fmaf(W.y, y0, acc0);
            accp = fmaf(W.z, yp, accp);
        }
        const float y2v = fmaxf(fmaf(mm, accm, fmaf(mp, accp, acc0 + c2)), 0.f);

        // wave-local y2 exchange: this thread's stored quad [4qq..4qq+3]
        f32x4 y;
        y.x = __shfl(y2v, srcl + 0, 64);
        y.y = __shfl(y2v, srcl + 1, 64);
        y.z = __shfl(y2v, srcl + 2, 64);
        y.w = __shfl(y2v, srcl + 3, 64);

        // 16 coalesced f32x4 stores (256B contiguous per 16-lane group)
        f32x4* out4 = (f32x4*)(out + (s0 + s) * 64 * 128);
        #pragma unroll
        for (int i = 0; i < 16; ++i) {
            f32x4 r;
            r.x = fmaf(w3r[i], y.x, b3r[i]);
            r.y = fmaf(w3r[i], y.y, b3r[i]);
            r.z = fmaf(w3r[i], y.z, b3r[i]);
            r.w = fmaf(w3r[i], y.w, b3r[i]);
            out4[(4 * i + g) * 32 + qq] = r;
        }
    }
}

extern "C" void kernel_launch(void* const* d_in, const int* in_sizes, int n_in,
                              void* d_out, int out_size, void* d_ws, size_t ws_size,
                              hipStream_t stream) {
    const float* x   = (const float*)d_in[0];   // node_features [B,E,N,T,1]
    // d_in[1] edge_features: unused by the reference computation
    const float* w1  = (const float*)d_in[2];
    const float* b1  = (const float*)d_in[3];
    const float* w2  = (const float*)d_in[4];
    const float* b2  = (const float*)d_in[5];
    const float* w3  = (const float*)d_in[6];
    const float* b3  = (const float*)d_in[7];
    const float* g1  = (const float*)d_in[8];
    const float* be1 = (const float*)d_in[9];
    const float* m1  = (const float*)d_in[10];
    const float* v1  = (const float*)d_in[11];
    const float* g2  = (const float*)d_in[12];
    const float* be2 = (const float*)d_in[13];
    const float* m2  = (const float*)d_in[14];
    const float* v2  = (const float*)d_in[15];

    const int T = 128;
    const int n_series = in_sizes[0] / T;       // 8192
    const int n_blocks = n_series / SER;        // 2048

    hnc_kernel<<<n_blocks, 128, 0, stream>>>(x, w1, b1, w2, b2, w3, b3,
                                             g1, be1, m1, v1, g2, be2, m2, v2,
                                             (float*)d_out);
}